// Round 11
// baseline (218.945 us; speedup 1.0000x reference)
//
#include <hip/hip_runtime.h>

typedef unsigned short u16;
typedef unsigned int u32;

#define BATCH 2
#define TTEXT 2048
#define DIM 1024
#define TMED 8
#define MTOK 256
#define HEADS 16
#define DHEAD 64
#define INNER 1024
#define TM 2048            // TMED * MTOK
#define QSCALE 0.125f      // DHEAD^-0.5
#define QCHUNK 64          // queries per attention block

typedef __attribute__((ext_vector_type(8))) short bf16x8;
typedef __attribute__((ext_vector_type(4))) float f32x4;

__device__ __forceinline__ float b2f(u16 u){
  union { float f; u32 i; } x; x.i = ((u32)u) << 16; return x.f;
}
__device__ __forceinline__ u16 f2b(float f){
  union { float f; u32 i; } x; x.f = f;
  u32 r = x.i + 0x7FFFu + ((x.i >> 16) & 1u);   // RNE
  return (u16)(r >> 16);
}

#define GLDS16(g, l) __builtin_amdgcn_global_load_lds( \
    (const __attribute__((address_space(1))) u32*)(g), \
    (__attribute__((address_space(3))) u32*)(l), 16, 0, 0)

// ================= prep: scan + LN + media cvt + 3 weight transposes =================
// One dispatch, block-partitioned:
//   [0,4096)      LN row
//   [4096,8192)   media fp32->bf16
//   [8192,12288)  weight transposes (Wq 1024 | Wout 1024 | Wkv 2048 blocks)
//   12288         media_locations scan
__global__ __launch_bounds__(256) void prep_kernel(const float* __restrict__ x,
                                                   const float* __restrict__ gamma,
                                                   const float* __restrict__ beta,
                                                   const float* __restrict__ media,
                                                   const float* __restrict__ Wq,
                                                   const float* __restrict__ Wkv,
                                                   const float* __restrict__ Wout,
                                                   const unsigned char* __restrict__ locs,
                                                   u16* __restrict__ xn,
                                                   u16* __restrict__ medb,
                                                   u16* __restrict__ Wqt,
                                                   u16* __restrict__ Wkvt,
                                                   u16* __restrict__ Woutt,
                                                   int* __restrict__ tt){
  __shared__ float tile[32][33];
  __shared__ int sd[256];
  __shared__ float ps[4], pss[4], mu_s, rs_s;
  int id = blockIdx.x, t = threadIdx.x;

  if (id < 4096){
    // ---- LayerNorm row ----
    int row = id;
    float4 v = *(const float4*)(x + (size_t)row * DIM + t * 4);
    float s  = v.x + v.y + v.z + v.w;
    float ss = v.x*v.x + v.y*v.y + v.z*v.z + v.w*v.w;
    #pragma unroll
    for (int off = 32; off; off >>= 1){ s += __shfl_xor(s, off); ss += __shfl_xor(ss, off); }
    int w = t >> 6;
    if ((t & 63) == 0){ ps[w] = s; pss[w] = ss; }
    __syncthreads();
    if (t == 0){
      float S = ps[0] + ps[1] + ps[2] + ps[3];
      float SS = pss[0] + pss[1] + pss[2] + pss[3];
      float mu = S * (1.f / DIM);
      float var = SS * (1.f / DIM) - mu * mu;
      mu_s = mu; rs_s = rsqrtf(var + 1e-5f);
    }
    __syncthreads();
    float mu = mu_s, rs = rs_s;
    float4 g  = *(const float4*)(gamma + t * 4);
    float4 be = *(const float4*)(beta + t * 4);
    ushort4 o;
    o.x = f2b((v.x - mu) * rs * g.x + be.x);
    o.y = f2b((v.y - mu) * rs * g.y + be.y);
    o.z = f2b((v.z - mu) * rs * g.z + be.z);
    o.w = f2b((v.w - mu) * rs * g.w + be.w);
    *(ushort4*)(xn + (size_t)row * DIM + t * 4) = o;
  } else if (id < 8192){
    // ---- media fp32 -> bf16 ----
    int i = ((id - 4096) * 256 + t) * 4;
    float4 v = *(const float4*)(media + i);
    ushort4 o;
    o.x = f2b(v.x); o.y = f2b(v.y); o.z = f2b(v.z); o.w = f2b(v.w);
    *(ushort4*)(medb + i) = o;
  } else if (id < 12288){
    // ---- weight transpose W[K][N] fp32 -> Wt[N][K] bf16 ----
    int z = id - 8192;
    const float* W; u16* Wt; int N, bx, by;
    if (z < 1024){ W = Wq;   Wt = Wqt;   N = 1024; bx = z & 31; by = z >> 5; }
    else if (z < 2048){ z -= 1024; W = Wout; Wt = Woutt; N = 1024; bx = z & 31; by = z >> 5; }
    else { z -= 2048; W = Wkv; Wt = Wkvt; N = 2048; bx = z & 63; by = z >> 6; }
    const int K = 1024;
    int tx = t & 31, ty = t >> 5;   // 32 x 8
    int n = bx * 32 + tx;
    #pragma unroll
    for (int i = 0; i < 32; i += 8)
      tile[ty + i][tx] = W[(size_t)(by * 32 + ty + i) * N + n];
    __syncthreads();
    int k2 = by * 32 + tx;
    #pragma unroll
    for (int i = 0; i < 32; i += 8)
      Wt[(size_t)(bx * 32 + ty + i) * K + k2] = f2b(tile[tx][ty + i]);
  } else {
    // ---- text_time scan (dtype-agnostic bool detect) ----
    int c = 0;
    for (int i = t; i < 4096; i += 256) c += (locs[i] != 0);
    sd[t] = c; __syncthreads();
    for (int off = 128; off; off >>= 1){
      if (t < off) sd[t] += sd[t + off];
      __syncthreads();
    }
    int is_byte = (sd[0] >= 9);
    __syncthreads();
    const int* as_int = (const int*)locs;
    for (int b = 0; b < BATCH; b++){
      int inc[8]; int s = 0;
      #pragma unroll
      for (int k = 0; k < 8; k++){
        int i = b * TTEXT + t * 8 + k;
        int v = is_byte ? (locs[i] != 0) : (as_int[i] != 0);
        s += v; inc[k] = s;
      }
      sd[t] = s; __syncthreads();
      for (int off = 1; off < 256; off <<= 1){
        int v = (t >= off) ? sd[t - off] : 0;
        __syncthreads();
        sd[t] += v;
        __syncthreads();
      }
      int excl = sd[t] - s;
      #pragma unroll
      for (int k = 0; k < 8; k++) tt[b * TTEXT + t * 8 + k] = excl + inc[k];
      __syncthreads();
    }
  }
}

// ================= MFMA GEMM body: C[.,N] = A[.,K] @ Bt[N,K]^T =================
// Double-buffered LDS, one barrier per K-step (round-10 proven structure).
// MODE 0: bf16 C.  MODE 1: fp32 C.  MODE 2: KV scatter (K token-major, V dim-major).
template<int MODE, int BN>
__device__ __forceinline__ void gemm_body(const u16* __restrict__ A,
                                          const u16* __restrict__ Bt,
                                          void* __restrict__ Cp,
                                          u16* __restrict__ C2p,
                                          int N, int K, int bx, int by,
                                          u16* As, u16* Bs){
  constexpr int BCOLS = BN / 32;
  int tid = threadIdx.x;
  int wave = tid >> 6, lane = tid & 63;
  int m0 = bx * 128, n0 = by * BN;
  int wm = (wave & 1) * 64, wn = (wave >> 1) * (BN / 2);
  int quad = lane >> 4, l16 = lane & 15;

  f32x4 acc[4][BCOLS];
  #pragma unroll
  for (int r = 0; r < 4; r++)
    #pragma unroll
    for (int c = 0; c < BCOLS; c++) acc[r][c] = (f32x4){0.f, 0.f, 0.f, 0.f};

  const u16* ag = A + (size_t)(m0 + wave * 32 + (lane >> 2)) * K + (lane & 3) * 8;
  const u16* bg;
  u16* asl0 = As + wave * 32 * 32;
  u16* bsl0;
  if (BN == 128){
    bg = Bt + (size_t)(n0 + wave * 32 + (lane >> 2)) * K + (lane & 3) * 8;
    bsl0 = Bs + wave * 32 * 32;
  } else {
    bg = Bt + (size_t)(n0 + wave * 16 + (lane >> 2)) * K + (lane & 3) * 8;
    bsl0 = Bs + wave * 16 * 32;
  }

  auto stage = [&](int k0, int buf){
    u16* asl = asl0 + buf * 128 * 32;
    u16* bsl = bsl0 + buf * BN * 32;
    GLDS16(ag + k0,                  asl);
    GLDS16(ag + k0 + 16 * (size_t)K, asl + 16 * 32);
    GLDS16(bg + k0,                  bsl);
    if (BN == 128) GLDS16(bg + k0 + 16 * (size_t)K, bsl + 16 * 32);
  };

  int steps = K >> 5;
  stage(0, 0);
  for (int s = 0; s < steps; s++){
    __syncthreads();                     // drains stage(s); frees other buf
    if (s + 1 < steps) stage((s + 1) << 5, (s + 1) & 1);
    const u16* Ab = As + (s & 1) * 128 * 32;
    const u16* Bb = Bs + (s & 1) * BN * 32;
    bf16x8 af[4], bf[BCOLS];
    #pragma unroll
    for (int r = 0; r < 4; r++)
      af[r] = *(const bf16x8*)&Ab[(wm + r * 16 + l16) * 32 + quad * 8];
    #pragma unroll
    for (int c = 0; c < BCOLS; c++)
      bf[c] = *(const bf16x8*)&Bb[(wn + c * 16 + l16) * 32 + quad * 8];
    #pragma unroll
    for (int r = 0; r < 4; r++)
      #pragma unroll
      for (int c = 0; c < BCOLS; c++)
        acc[r][c] = __builtin_amdgcn_mfma_f32_16x16x32_bf16(af[r], bf[c], acc[r][c], 0, 0, 0);
  }

  #pragma unroll
  for (int r = 0; r < 4; r++){
    #pragma unroll
    for (int c = 0; c < BCOLS; c++){
      int rG = m0 + wm + r * 16 + quad * 4;      // + i
      int cG = n0 + wn + c * 16 + l16;
      if (MODE == 0){
        u16* C = (u16*)Cp;
        #pragma unroll
        for (int i = 0; i < 4; i++)
          C[(size_t)(rG + i) * N + cG] = f2b(acc[r][c][i]);
      } else if (MODE == 1){
        float* C = (float*)Cp;
        #pragma unroll
        for (int i = 0; i < 4; i++)
          C[(size_t)(rG + i) * N + cG] = acc[r][c][i];
      } else {
        int bb = rG >> 11, jj = rG & 2047;       // 4-row groups never cross batch
        if (cG < INNER){
          int hh = cG >> 6, dd = cG & 63;
          u16* kp = (u16*)Cp + (((size_t)bb * HEADS + hh) * TM + jj) * DHEAD + dd;
          #pragma unroll
          for (int i = 0; i < 4; i++)
            kp[(size_t)i * DHEAD] = f2b(acc[r][c][i]);
        } else {
          int cc = cG - INNER;
          int hh = cc >> 6, dd = cc & 63;
          u16* vp = C2p + (((size_t)bb * HEADS + hh) * DHEAD + dd) * TM + jj;
          ushort4 o;
          o.x = f2b(acc[r][c][0]); o.y = f2b(acc[r][c][1]);
          o.z = f2b(acc[r][c][2]); o.w = f2b(acc[r][c][3]);
          *(ushort4*)vp = o;
        }
      }
    }
  }
}

// Q-proj (blocks 0..511, 128x64) and KV-proj (blocks 512..1023, 128x128) in one dispatch.
__global__ __launch_bounds__(256) void gemm_qkv(const u16* __restrict__ xn,
                                                const u16* __restrict__ Wqt,
                                                u16* __restrict__ qb,
                                                const u16* __restrict__ medb,
                                                const u16* __restrict__ Wkvt,
                                                u16* __restrict__ kB,
                                                u16* __restrict__ vT){
  __shared__ u16 As[2 * 128 * 32];
  __shared__ u16 Bs[2 * 128 * 32];
  int id = blockIdx.x;
  if (id < 512){
    gemm_body<0, 64>(xn, Wqt, qb, nullptr, 1024, 1024, id & 31, id >> 5, As, Bs);
  } else {
    int j = id - 512;
    gemm_body<2, 128>(medb, Wkvt, kB, vT, 2048, 1024, j & 31, j >> 5, As, Bs);
  }
}

// out-proj: 128x64 tiles, fp32 output.
__global__ __launch_bounds__(256) void gemm_out(const u16* __restrict__ ao,
                                                const u16* __restrict__ Woutt,
                                                float* __restrict__ out){
  __shared__ u16 As[2 * 128 * 32];
  __shared__ u16 Bs[2 * 64 * 32];
  int id = blockIdx.x;
  gemm_body<1, 64>(ao, Woutt, out, nullptr, 1024, 1024, id & 31, id >> 5, As, Bs);
}

// ================= MFMA attention: 64 queries x 1 head per block =================
// Full 256-key K staged once per media block (one burst, 32 uninterrupted MFMAs);
// P (A-layout) and final O strip overlay the K region; V staged per 128-key half.
// 6 barriers per media block (was 8). XCD swizzle + registered O select +
// single coalesced output write (round-9/10 proven pieces).
__global__ __launch_bounds__(256, 2) void attn_kernel(const u16* __restrict__ qb,
                                                      const u16* __restrict__ kB,
                                                      const u16* __restrict__ vT,
                                                      const int* __restrict__ tt,
                                                      u16* __restrict__ ao){
  __shared__ u16 Kf[256 * 72];         // K [256 keys][72]; reused: P [64 q][136], O strip [64 q][72]
  __shared__ u16 Vh[64 * 136];         // V half [64 d][128 keys pad->136]
  __shared__ int miq[QCHUNK];
  __shared__ int present[8];

  int t = threadIdx.x;
  int wave = t >> 6, lane = t & 63, quad = lane >> 4, l16 = lane & 15;
  int id = blockIdx.x;
  int pair = id & 31, chunk = id >> 5;  // XCD swizzle: id%8 fixed per (b,h)
  int b = pair >> 4, h = pair & 15;
  int q0 = chunk * QCHUNK;

  if (t < 8) present[t] = 0;
  __syncthreads();
  if (t < QCHUNK){
    int v = tt[b * TTEXT + q0 + t] - 1;
    miq[t] = v;
    if (v >= 0 && v < 8) present[v] = 1;
  }
  const u16* qrow = qb + (size_t)(b * TTEXT + q0 + wave * 16 + l16) * INNER
                       + h * DHEAD + quad * 8;
  bf16x8 aq0 = *(const bf16x8*)(qrow);
  bf16x8 aq1 = *(const bf16x8*)(qrow + 32);
  __syncthreads();                     // miq/present visible

  int myi[4];
  #pragma unroll
  for (int i = 0; i < 4; i++) myi[i] = miq[wave * 16 + quad * 4 + i];

  const size_t kvh = (size_t)b * HEADS + h;
  const u16* kg = kB + kvh * TM * DHEAD;            // [token][64]
  const u16* vg = vT + kvh * DHEAD * TM;            // [d][TM]

  f32x4 Osel[4];
  #pragma unroll
  for (int c4 = 0; c4 < 4; c4++) Osel[c4] = (f32x4){0.f, 0.f, 0.f, 0.f};

  for (int mi = 0; mi < 8; mi++){
    if (!present[mi]) continue;                     // block-uniform

    // ---- stage all 256 keys into Kf (one burst) ----
    __syncthreads();   // prior Kf reads (prev mi's P) done
    #pragma unroll
    for (int p = 0; p < 8; p++){
      int idx = p * 256 + t;
      int row = idx >> 3, seg = idx & 7;
      uint4 v = *(const uint4*)(kg + (size_t)(mi * MTOK + row) * DHEAD + seg * 8);
      *(uint4*)(Kf + row * 72 + seg * 8) = v;
    }
    __syncthreads();

    // ---- QK^T: 32 uninterrupted MFMAs ----
    f32x4 S[16];
    #pragma unroll
    for (int c = 0; c < 16; c++) S[c] = (f32x4){0.f, 0.f, 0.f, 0.f};
    #pragma unroll
    for (int ks = 0; ks < 2; ks++){
      bf16x8 aq = ks ? aq1 : aq0;
      #pragma unroll
      for (int c = 0; c < 16; c++){
        bf16x8 bk = *(const bf16x8*)&Kf[(c * 16 + l16) * 72 + ks * 32 + quad * 8];
        S[c] = __builtin_amdgcn_mfma_f32_16x16x32_bf16(aq, bk, S[c], 0, 0, 0);
      }
    }

    // ---- softmax in regs; lane holds S[row=quad*4+i][key=c*16+l16] ----
    float mx[4], sm[4];
    #pragma unroll
    for (int i = 0; i < 4; i++) mx[i] = -1e30f;
    #pragma unroll
    for (int c = 0; c < 16; c++)
      #pragma unroll
      for (int i = 0; i < 4; i++){
        float sv = S[c][i] * QSCALE; S[c][i] = sv; mx[i] = fmaxf(mx[i], sv);
      }
    #pragma unroll
    for (int off = 1; off < 16; off <<= 1)
      #pragma unroll
      for (int i = 0; i < 4; i++) mx[i] = fmaxf(mx[i], __shfl_xor(mx[i], off));
    #pragma unroll
    for (int i = 0; i < 4; i++) sm[i] = 0.f;
    #pragma unroll
    for (int c = 0; c < 16; c++)
      #pragma unroll
      for (int i = 0; i < 4; i++){
        float e = __expf(S[c][i] - mx[i]); S[c][i] = e; sm[i] += e;
      }
    #pragma unroll
    for (int off = 1; off < 16; off <<= 1)
      #pragma unroll
      for (int i = 0; i < 4; i++) sm[i] += __shfl_xor(sm[i], off);
    #pragma unroll
    for (int i = 0; i < 4; i++) sm[i] = 1.f / sm[i];

    // ---- PV over two key halves; P half -> Kf region (A-layout), V half -> Vh ----
    f32x4 O[4];
    #pragma unroll
    for (int c4 = 0; c4 < 4; c4++) O[c4] = (f32x4){0.f, 0.f, 0.f, 0.f};
    #pragma unroll
    for (int kh = 0; kh < 2; kh++){
      __syncthreads();   // Kf QK reads done (kh=0) / prior P+Vh reads done (kh=1)
      #pragma unroll
      for (int c = 0; c < 8; c++)
        #pragma unroll
        for (int i = 0; i < 4; i++)
          Kf[(wave * 16 + quad * 4 + i) * 136 + c * 16 + l16] = f2b(S[kh * 8 + c][i] * sm[i]);
      #pragma unroll
      for (int p = 0; p < 4; p++){
        int idx = p * 256 + t;
        int row = idx >> 4, seg = idx & 15;
        uint4 v = *(const uint4*)(vg + (size_t)row * TM + mi * MTOK + kh * 128 + seg * 8);
        *(uint4*)(Vh + row * 136 + seg * 8) = v;
      }
      __syncthreads();
      #pragma unroll
      for (int k0 = 0; k0 < 4; k0++){
        bf16x8 ap = *(const bf16x8*)&Kf[(wave * 16 + l16) * 136 + k0 * 32 + quad * 8];
        #pragma unroll
        for (int c4 = 0; c4 < 4; c4++){
          bf16x8 bv = *(const bf16x8*)&Vh[(c4 * 16 + l16) * 136 + k0 * 32 + quad * 8];
          O[c4] = __builtin_amdgcn_mfma_f32_16x16x32_bf16(ap, bv, O[c4], 0, 0, 0);
        }
      }
    }

    // ---- registered output select (each row matches <=1 mi) ----
    #pragma unroll
    for (int c4 = 0; c4 < 4; c4++)
      #pragma unroll
      for (int i = 0; i < 4; i++)
        Osel[c4][i] = (myi[i] == mi) ? O[c4][i] : Osel[c4][i];
  }

  __syncthreads();   // all waves' last P reads done before O strip overwrites Kf
  // single coalesced O write via intra-wave LDS transpose (own strip)
  #pragma unroll
  for (int c4 = 0; c4 < 4; c4++)
    #pragma unroll
    for (int i = 0; i < 4; i++)
      Kf[(wave * 16 + quad * 4 + i) * 72 + c4 * 16 + l16] = f2b(Osel[c4][i]);
  int r = lane >> 2, sidx = lane & 3;
  #pragma unroll
  for (int p = 0; p < 2; p++){
    int seg = p * 4 + sidx;
    uint4 v = *(const uint4*)&Kf[(wave * 16 + r) * 72 + seg * 8];
    *(uint4*)(ao + (size_t)(b * TTEXT + q0 + wave * 16 + r) * INNER + h * DHEAD + seg * 8) = v;
  }
}

extern "C" void kernel_launch(void* const* d_in, const int* in_sizes, int n_in,
                              void* d_out, int out_size, void* d_ws, size_t ws_size,
                              hipStream_t stream){
  const float* x      = (const float*)d_in[0];
  const float* media  = (const float*)d_in[1];
  const unsigned char* locs = (const unsigned char*)d_in[2];
  const float* gamma  = (const float*)d_in[3];
  const float* beta   = (const float*)d_in[4];
  const float* Wq     = (const float*)d_in[5];
  const float* Wkv    = (const float*)d_in[6];
  const float* Wout   = (const float*)d_in[7];

  // workspace layout (~58 MB), all bf16 intermediates
  char* ws = (char*)d_ws;
  int* tt    = (int*)ws;   ws += 16384;
  u16* xn    = (u16*)ws;   ws += (size_t)4096 * 1024 * 2;   // [B*T][DIM]
  u16* medb  = (u16*)ws;   ws += (size_t)4096 * 1024 * 2;   // [B*TM][DIM]
  u16* Wqt   = (u16*)ws;   ws += (size_t)1024 * 1024 * 2;   // [INNER][DIM]
  u16* Wkvt  = (u16*)ws;   ws += (size_t)2048 * 1024 * 2;   // [2*INNER][DIM]
  u16* Woutt = (u16*)ws;   ws += (size_t)1024 * 1024 * 2;   // [DIM][INNER]
  u16* qb    = (u16*)ws;   ws += (size_t)4096 * 1024 * 2;   // [B*T][INNER]
  u16* kB    = (u16*)ws;   ws += (size_t)4096 * 1024 * 2;   // [B,H,TM,64] token-major
  u16* vT    = (u16*)ws;   ws += (size_t)4096 * 1024 * 2;   // [B,H,64,TM] dim-major
  u16* ao    = (u16*)ws;   ws += (size_t)4096 * 1024 * 2;   // [B*T][INNER]

  prep_kernel<<<12289, 256, 0, stream>>>(x, gamma, beta, media, Wq, Wkv, Wout, locs,
                                         xn, medb, Wqt, Wkvt, Woutt, tt);
  gemm_qkv<<<1024, 256, 0, stream>>>(xn, Wqt, qb, medb, Wkvt, kB, vT);
  attn_kernel<<<1024, 256, 0, stream>>>(qb, kB, vT, tt, ao);
  gemm_out<<<512, 256, 0, stream>>>(ao, Woutt, (float*)d_out);
}